// Round 9
// baseline (134.356 us; speedup 1.0000x reference)
//
#include <hip/hip_runtime.h>

#define E_DIM 69120
#define N1 60
#define H 32
#define CC 3
#define TEB 128
#define NB2 (E_DIM / TEB)   // 540
#define SDS 132             // ds tile stride (floats); rows 16B-aligned
#define SBF 36              // chain-buffer row stride (floats); 16B-aligned rows
#define TSTR 132            // bufT row stride (floats)
#define PSZ (N1 * H)        // 1920
#define TROW(h) ((((h) & 3) << 3) | ((h) >> 2))

// LDS: ds[60*132]=7920f | buf[4608]f (in-place chain: [128][36] rows, then
// bufT[32][132] transposed overlay) -> 12,528 f = 50,112 B -> 3 blocks/CU.

__device__ __forceinline__ float relu_dot4(const float4 d, const float w, const float4 t) {
    return fmaxf(fmaf(d.x, w, t.x), 0.f) + fmaxf(fmaf(d.y, w, t.y), 0.f)
         + fmaxf(fmaf(d.z, w, t.z), 0.f) + fmaxf(fmaf(d.w, w, t.w), 0.f);
}

// =====================================================================
// kA13: v_bar chain + alpha partials. 512 thr: ph1-3 (eL 0..127, hq 0..3)
// =====================================================================
template<bool ATOMIC>
__global__ __launch_bounds__(512, 6) void kA13(
    const float* __restrict__ d,
    const float* __restrict__ Wfvb, const float* __restrict__ bfvb,
    const float* __restrict__ Wgvb, const float* __restrict__ bgvb,
    const float* __restrict__ Wfu,  const float* __restrict__ bfu,
    float* __restrict__ outp)
{
    __shared__ __align__(16) float ds[N1 * SDS];
    __shared__ __align__(16) float buf[4608];
    const int tid = threadIdx.x;
    const long sE = (long)blockIdx.x * TEB;

    // ph0: stage support tile
    for (int i = tid; i < N1 * (TEB / 4); i += 512) {
        const int n = i >> 5, c = (i & 31) * 4;
        *(float4*)(ds + n * SDS + c) = *(const float4*)(d + (long)n * E_DIM + sE + c);
    }
    __syncthreads();

    const int eL = tid & 127, h0 = (tid >> 7) * 8;

    // ph1: t1 = mean_n relu(d*wf+bf); 8 h/thread, dual acc
    {
        float wf[8], bf[8], ta[8], tb[8];
        #pragma unroll
        for (int j = 0; j < 8; ++j) { wf[j] = Wfvb[h0+j]; bf[j] = bfvb[h0+j]; ta[j] = 0.f; tb[j] = 0.f; }
        const float* dp = ds + eL;
        #pragma unroll 2
        for (int n = 0; n < N1; n += 2) {
            const float dv0 = dp[n * SDS];
            const float dv1 = dp[(n + 1) * SDS];
            #pragma unroll
            for (int j = 0; j < 8; ++j) {
                ta[j] += fmaxf(fmaf(dv0, wf[j], bf[j]), 0.f);
                tb[j] += fmaxf(fmaf(dv1, wf[j], bf[j]), 0.f);
            }
        }
        float o[8];
        #pragma unroll
        for (int j = 0; j < 8; ++j) o[j] = (ta[j] + tb[j]) * (1.f / N1);
        *(float4*)(buf + eL * SBF + h0)     = make_float4(o[0], o[1], o[2], o[3]);
        *(float4*)(buf + eL * SBF + h0 + 4) = make_float4(o[4], o[5], o[6], o[7]);
    }
    __syncthreads();   // B1: t1 visible

    float row[32];

    // ph2: vb = relu(t1 @ Wgvb + bgvb), in-place (read row -> sync -> write)
    #pragma unroll
    for (int q = 0; q < 8; ++q)
        *(float4*)(row + q * 4) = *(const float4*)(buf + eL * SBF + q * 4);
    __syncthreads();   // B2: all reads done
    {
        float acc[8];
        #pragma unroll
        for (int j = 0; j < 8; ++j) acc[j] = bgvb[h0 + j];
        #pragma unroll
        for (int k = 0; k < H; ++k) {
            const float t = row[k];
            #pragma unroll
            for (int j = 0; j < 8; ++j) acc[j] = fmaf(t, Wgvb[k * H + h0 + j], acc[j]);
        }
        #pragma unroll
        for (int j = 0; j < 8; ++j) acc[j] = fmaxf(acc[j], 0.f);
        *(float4*)(buf + eL * SBF + h0)     = make_float4(acc[0], acc[1], acc[2], acc[3]);
        *(float4*)(buf + eL * SBF + h0 + 4) = make_float4(acc[4], acc[5], acc[6], acc[7]);
    }
    __syncthreads();   // B3: vb visible

    // ph3: vw = vb @ Wu_v + b_fu -> transposed TROW rows (in-place overlay)
    #pragma unroll
    for (int q = 0; q < 8; ++q)
        *(float4*)(row + q * 4) = *(const float4*)(buf + eL * SBF + q * 4);
    __syncthreads();   // B4: all reads done
    {
        float acc[8];
        #pragma unroll
        for (int j = 0; j < 8; ++j) acc[j] = bfu[h0 + j];
        #pragma unroll
        for (int k = 0; k < H; ++k) {
            const float t = row[k];
            #pragma unroll
            for (int j = 0; j < 8; ++j) acc[j] = fmaf(t, Wfu[k * H + h0 + j], acc[j]);
        }
        #pragma unroll
        for (int j = 0; j < 8; ++j) buf[TROW(h0 + j) * TSTR + eL] = acc[j];
    }
    __syncthreads();   // B5: vw visible

    // ph4: alpha partials; n-pair x 4h threads (240 active)
    if (tid < (N1 / 2) * 8) {
        const int np = tid >> 3, hg = tid & 7, hb = hg * 4;
        const int n0 = 2 * np, n1 = n0 + 1;
        float wud[4], a0[4], a1[4];
        #pragma unroll
        for (int j = 0; j < 4; ++j) { wud[j] = Wfu[H * H + hb + j]; a0[j] = 0.f; a1[j] = 0.f; }
        const float* r0 = ds + n0 * SDS;
        const float* r1 = ds + n1 * SDS;
        for (int e8 = 0; e8 < TEB; e8 += 8) {
            const float4 d0a = *(const float4*)(r0 + e8);
            const float4 d0b = *(const float4*)(r0 + e8 + 4);
            const float4 d1a = *(const float4*)(r1 + e8);
            const float4 d1b = *(const float4*)(r1 + e8 + 4);
            #pragma unroll
            for (int j = 0; j < 4; ++j) {
                const float* wr = buf + (j * 8 + hg) * TSTR + e8;  // TROW(hb+j)=j*8+hg
                const float4 wA = *(const float4*)(wr);
                const float4 wB = *(const float4*)(wr + 4);
                a0[j] += relu_dot4(d0a, wud[j], wA) + relu_dot4(d0b, wud[j], wB);
                a1[j] += relu_dot4(d1a, wud[j], wA) + relu_dot4(d1b, wud[j], wB);
            }
        }
        if (ATOMIC) {
            float* p0 = outp + n0 * H + hb;
            float* p1 = outp + n1 * H + hb;
            #pragma unroll
            for (int j = 0; j < 4; ++j) { atomicAdd(&p0[j], a0[j]); atomicAdd(&p1[j], a1[j]); }
        } else {
            float* base = outp + (long)blockIdx.x * PSZ;
            *(float4*)(base + n0 * H + hb) = make_float4(a0[0], a0[1], a0[2], a0[3]);
            *(float4*)(base + n1 * H + hb) = make_float4(a1[0], a1[1], a1[2], a1[3]);
        }
    }
}

// =====================================================================
// kCf13: fused v-chain + z partials. u via uniform global loads; query
// staged into ds (dead after ph1) during ph2's read segment.
// =====================================================================
template<bool ATOMIC>
__global__ __launch_bounds__(512, 6) void kCf13(
    const float* __restrict__ d, const float* __restrict__ d2,
    const float* __restrict__ uwb,
    const float* __restrict__ Wfvc,
    const float* __restrict__ Wgvc, const float* __restrict__ bgvc,
    const float* __restrict__ Wfz,  const float* __restrict__ bfz,
    float* __restrict__ outp)
{
    __shared__ __align__(16) float ds[N1 * SDS];
    __shared__ __align__(16) float buf[4608];
    const int tid = threadIdx.x;
    const long sE = (long)blockIdx.x * TEB;

    // ph0: stage support tile
    for (int i = tid; i < N1 * (TEB / 4); i += 512) {
        const int n = i >> 5, c = (i & 31) * 4;
        *(float4*)(ds + n * SDS + c) = *(const float4*)(d + (long)n * E_DIM + sE + c);
    }
    __syncthreads();

    const int eL = tid & 127, h0 = (tid >> 7) * 8;

    // ph1: m = mean_n relu(d*wvd + u[n,h]); u via wave-uniform global loads
    {
        float wvd[8], ma[8], mb[8];
        #pragma unroll
        for (int j = 0; j < 8; ++j) { wvd[j] = Wfvc[H * H + h0 + j]; ma[j] = 0.f; mb[j] = 0.f; }
        const float* dp = ds + eL;
        #pragma unroll 2
        for (int n = 0; n < N1; n += 2) {
            const float dv0 = dp[n * SDS];
            const float dv1 = dp[(n + 1) * SDS];
            const float4 u0a = *(const float4*)(uwb + n * H + h0);
            const float4 u0b = *(const float4*)(uwb + n * H + h0 + 4);
            const float4 u1a = *(const float4*)(uwb + (n + 1) * H + h0);
            const float4 u1b = *(const float4*)(uwb + (n + 1) * H + h0 + 4);
            const float u0[8] = {u0a.x,u0a.y,u0a.z,u0a.w,u0b.x,u0b.y,u0b.z,u0b.w};
            const float u1[8] = {u1a.x,u1a.y,u1a.z,u1a.w,u1b.x,u1b.y,u1b.z,u1b.w};
            #pragma unroll
            for (int j = 0; j < 8; ++j) {
                ma[j] += fmaxf(fmaf(dv0, wvd[j], u0[j]), 0.f);
                mb[j] += fmaxf(fmaf(dv1, wvd[j], u1[j]), 0.f);
            }
        }
        float o[8];
        #pragma unroll
        for (int j = 0; j < 8; ++j) o[j] = (ma[j] + mb[j]) * (1.f / N1);
        *(float4*)(buf + eL * SBF + h0)     = make_float4(o[0], o[1], o[2], o[3]);
        *(float4*)(buf + eL * SBF + h0 + 4) = make_float4(o[4], o[5], o[6], o[7]);
    }
    __syncthreads();   // B1 (ds reads of support all done)

    float row[32];

    // ph2 read segment + query staging into ds (support dead)
    #pragma unroll
    for (int q = 0; q < 8; ++q)
        *(float4*)(row + q * 4) = *(const float4*)(buf + eL * SBF + q * 4);
    for (int i = tid; i < N1 * (TEB / 4); i += 512) {
        const int n = i >> 5, c = (i & 31) * 4;
        *(float4*)(ds + n * SDS + c) = *(const float4*)(d2 + (long)n * E_DIM + sE + c);
    }
    __syncthreads();   // B2
    {
        float acc[8];
        #pragma unroll
        for (int j = 0; j < 8; ++j) acc[j] = bgvc[h0 + j];
        #pragma unroll
        for (int k = 0; k < H; ++k) {
            const float t = row[k];
            #pragma unroll
            for (int j = 0; j < 8; ++j) acc[j] = fmaf(t, Wgvc[k * H + h0 + j], acc[j]);
        }
        #pragma unroll
        for (int j = 0; j < 8; ++j) acc[j] = fmaxf(acc[j], 0.f);
        *(float4*)(buf + eL * SBF + h0)     = make_float4(acc[0], acc[1], acc[2], acc[3]);
        *(float4*)(buf + eL * SBF + h0 + 4) = make_float4(acc[4], acc[5], acc[6], acc[7]);
    }
    __syncthreads();   // B3

    // ph3: vz = v @ Wz_v + b_fz -> TROW rows
    #pragma unroll
    for (int q = 0; q < 8; ++q)
        *(float4*)(row + q * 4) = *(const float4*)(buf + eL * SBF + q * 4);
    __syncthreads();   // B4
    {
        float acc[8];
        #pragma unroll
        for (int j = 0; j < 8; ++j) acc[j] = bfz[h0 + j];
        #pragma unroll
        for (int k = 0; k < H; ++k) {
            const float t = row[k];
            #pragma unroll
            for (int j = 0; j < 8; ++j) acc[j] = fmaf(t, Wfz[k * H + h0 + j], acc[j]);
        }
        #pragma unroll
        for (int j = 0; j < 8; ++j) buf[TROW(h0 + j) * TSTR + eL] = acc[j];
    }
    __syncthreads();   // B5

    // ph4: z partials over staged QUERY rows
    if (tid < (N1 / 2) * 8) {
        const int np = tid >> 3, hg = tid & 7, hb = hg * 4;
        const int n0 = 2 * np, n1 = n0 + 1;
        float wzd[4], a0[4], a1[4];
        #pragma unroll
        for (int j = 0; j < 4; ++j) { wzd[j] = Wfz[H * H + hb + j]; a0[j] = 0.f; a1[j] = 0.f; }
        const float* r0 = ds + n0 * SDS;
        const float* r1 = ds + n1 * SDS;
        for (int e8 = 0; e8 < TEB; e8 += 8) {
            const float4 d0a = *(const float4*)(r0 + e8);
            const float4 d0b = *(const float4*)(r0 + e8 + 4);
            const float4 d1a = *(const float4*)(r1 + e8);
            const float4 d1b = *(const float4*)(r1 + e8 + 4);
            #pragma unroll
            for (int j = 0; j < 4; ++j) {
                const float* wr = buf + (j * 8 + hg) * TSTR + e8;
                const float4 wA = *(const float4*)(wr);
                const float4 wB = *(const float4*)(wr + 4);
                a0[j] += relu_dot4(d0a, wzd[j], wA) + relu_dot4(d0b, wzd[j], wB);
                a1[j] += relu_dot4(d1a, wzd[j], wA) + relu_dot4(d1b, wzd[j], wB);
            }
        }
        if (ATOMIC) {
            float* p0 = outp + n0 * H + hb;
            float* p1 = outp + n1 * H + hb;
            #pragma unroll
            for (int j = 0; j < 4; ++j) { atomicAdd(&p0[j], a0[j]); atomicAdd(&p1[j], a1[j]); }
        } else {
            float* base = outp + (long)blockIdx.x * PSZ;
            *(float4*)(base + n0 * H + hb) = make_float4(a0[0], a0[1], a0[2], a0[3]);
            *(float4*)(base + n1 * H + hb) = make_float4(a1[0], a1[1], a1[2], a1[3]);
        }
    }
}

// reduce part[NB2][PSZ] -> out[PSZ]; grid = PSZ/16 = 120 blocks
__global__ __launch_bounds__(256) void kR(
    const float* __restrict__ part, float* __restrict__ out)
{
    __shared__ float red[16][17];
    const int tid = threadIdx.x;
    const int oLoc = tid & 15, c = tid >> 4;
    const int o = blockIdx.x * 16 + oLoc;
    const int b0 = c * 34;
    const int bN = (NB2 - b0 < 34) ? (NB2 - b0) : 34;
    const float* p = part + (long)b0 * PSZ + o;
    float s = 0.f;
    #pragma unroll 2
    for (int b = 0; b < bN; ++b) s += p[(long)b * PSZ];
    red[c][oLoc] = s;
    __syncthreads();
    if (tid < 16) {
        float t = 0.f;
        #pragma unroll
        for (int ci = 0; ci < 16; ++ci) t += red[ci][tid];
        out[blockIdx.x * 16 + tid] = t;
    }
}

__global__ __launch_bounds__(1024) void kB(
    const float* __restrict__ alphaAcc, const int* __restrict__ label,
    const float* __restrict__ Wfvb, const float* __restrict__ bfvb,
    const float* __restrict__ Wgvb, const float* __restrict__ bgvb,
    const float* __restrict__ Wfu,  const float* __restrict__ bfu,
    const float* __restrict__ Wgu,  const float* __restrict__ bgu,
    const float* __restrict__ Wfvc, const float* __restrict__ bfvc,
    float* __restrict__ uwb)
{
    __shared__ float up_l[N1 * H];
    __shared__ float un_l[N1 * H];
    __shared__ float cb_l[CC * H];
    __shared__ float cw_l[CC * H];
    __shared__ int   cnt[CC];
    const int tid = threadIdx.x;

    if (tid < CC) cnt[tid] = 0;
    __syncthreads();
    if (tid < N1) atomicAdd(&cnt[label[tid]], 1);
    __syncthreads();

    if (tid < CC * H) {
        const int c = tid / H, h = tid % H;
        const float nc = (float)cnt[c];
        float s = bgvb[h];
        #pragma unroll
        for (int k = 0; k < H; ++k) {
            const float t1c = (nc * fmaxf(Wfvb[k] + bfvb[k], 0.f) +
                               ((float)N1 - nc) * fmaxf(bfvb[k], 0.f)) * (1.f / N1);
            s = fmaf(t1c, Wgvb[k * H + h], s);
        }
        cb_l[tid] = fmaxf(s, 0.f);
    }
    __syncthreads();
    if (tid < CC * H) {
        const int c = tid / H, h = tid % H;
        float s = bfu[h];
        #pragma unroll
        for (int k = 0; k < H; ++k) s = fmaf(cb_l[c * H + k], Wfu[k * H + h], s);
        cw_l[tid] = s;
    }
    __syncthreads();
    for (int t = tid; t < N1 * H; t += 1024) {
        const int n = t >> 5, h = t & 31;
        const int ln = label[n];
        const float wud = Wfu[H * H + h];
        float s = 0.f;
        #pragma unroll
        for (int c = 0; c < CC; ++c)
            s += fmaxf(cw_l[c * H + h] + ((c == ln) ? wud : 0.f), 0.f);
        up_l[t] = alphaAcc[t] * (1.f / E_DIM) + s * (1.f / CC);
    }
    __syncthreads();
    for (int t = tid; t < N1 * H; t += 1024) {
        const int n = t >> 5, h = t & 31;
        float s = bgu[h];
        #pragma unroll
        for (int k = 0; k < H; ++k) s = fmaf(up_l[n * H + k], Wgu[k * H + h], s);
        un_l[t] = fmaxf(s, 0.f);
    }
    __syncthreads();
    for (int t = tid; t < N1 * H; t += 1024) {
        const int n = t >> 5, h = t & 31;
        float s = bfvc[h];
        #pragma unroll
        for (int k = 0; k < H; ++k) s = fmaf(un_l[n * H + k], Wfvc[k * H + h], s);
        uwb[t] = s;
    }
}

__global__ __launch_bounds__(1024) void kD(
    const float* __restrict__ zAcc,
    const float* __restrict__ Wgz, const float* __restrict__ bgz,
    float* __restrict__ out)
{
    __shared__ float z_l[N1 * H];
    const int tid = threadIdx.x;
    for (int t = tid; t < N1 * H; t += 1024) z_l[t] = zAcc[t] * (1.f / E_DIM);
    __syncthreads();
    for (int t = tid; t < N1 * H; t += 1024) {
        const int n = t >> 5, h = t & 31;
        float s = bgz[h];
        #pragma unroll
        for (int k = 0; k < H; ++k) s = fmaf(z_l[n * H + k], Wgz[k * H + h], s);
        out[t] = fmaxf(s, 0.f);
    }
}

extern "C" void kernel_launch(void* const* d_in, const int* in_sizes, int n_in,
                              void* d_out, int out_size, void* d_ws, size_t ws_size,
                              hipStream_t stream)
{
    const float* sup  = (const float*)d_in[0];
    const int*   lab  = (const int*)d_in[1];
    const float* qry  = (const float*)d_in[2];
    const float* Wfvb = (const float*)d_in[3];
    const float* bfvb = (const float*)d_in[4];
    const float* Wgvb = (const float*)d_in[5];
    const float* bgvb = (const float*)d_in[6];
    const float* Wfu  = (const float*)d_in[7];
    const float* bfu  = (const float*)d_in[8];
    const float* Wgu  = (const float*)d_in[9];
    const float* bgu  = (const float*)d_in[10];
    const float* Wfvc = (const float*)d_in[11];
    const float* bfvc = (const float*)d_in[12];
    const float* Wgvc = (const float*)d_in[13];
    const float* bgvc = (const float*)d_in[14];
    const float* Wfz  = (const float*)d_in[15];
    const float* bfz  = (const float*)d_in[16];
    const float* Wgz  = (const float*)d_in[17];
    const float* bgz  = (const float*)d_in[18];
    float* out = (float*)d_out;

    float* alphaAcc = (float*)d_ws;
    float* zAcc     = alphaAcc + PSZ;
    float* uwb      = zAcc + PSZ;
    float* partA    = uwb + PSZ;
    float* partZ    = partA + (size_t)NB2 * PSZ;

    const size_t needMain = (3 * (size_t)PSZ + 2 * (size_t)NB2 * PSZ) * sizeof(float);

    if (ws_size >= needMain) {
        kA13<false><<<NB2, 512, 0, stream>>>(sup, Wfvb, bfvb, Wgvb, bgvb, Wfu, bfu, partA);
        kR<<<PSZ / 16, 256, 0, stream>>>(partA, alphaAcc);
        kB<<<1, 1024, 0, stream>>>(alphaAcc, lab, Wfvb, bfvb, Wgvb, bgvb, Wfu, bfu,
                                   Wgu, bgu, Wfvc, bfvc, uwb);
        kCf13<false><<<NB2, 512, 0, stream>>>(sup, qry, uwb, Wfvc, Wgvc, bgvc, Wfz, bfz, partZ);
        kR<<<PSZ / 16, 256, 0, stream>>>(partZ, zAcc);
        kD<<<1, 1024, 0, stream>>>(zAcc, Wgz, bgz, out);
    } else {
        (void)hipMemsetAsync(alphaAcc, 0, 2 * PSZ * sizeof(float), stream);
        kA13<true><<<NB2, 512, 0, stream>>>(sup, Wfvb, bfvb, Wgvb, bgvb, Wfu, bfu, alphaAcc);
        kB<<<1, 1024, 0, stream>>>(alphaAcc, lab, Wfvb, bfvb, Wgvb, bgvb, Wfu, bfu,
                                   Wgu, bgu, Wfvc, bfvc, uwb);
        kCf13<true><<<NB2, 512, 0, stream>>>(sup, qry, uwb, Wfvc, Wgvc, bgvc, Wfz, bfz, zAcc);
        kD<<<1, 1024, 0, stream>>>(zAcc, Wgz, bgz, out);
    }
}